// Round 1
// baseline (1440.052 us; speedup 1.0000x reference)
//
#include <hip/hip_runtime.h>

#define BB 8
#define HH 8
#define NSEQ 1024
#define CD 128
#define QT 32
#define KT 32
#define LDP 132      // padded LDS row stride (floats); 132%4==0 keeps float4 aligned
#define SBLD 33      // score tile row stride
#define NV 30        // vectors per token

__global__ __launch_bounds__(256, 2)
void ipa_fused(const float* __restrict__ qg, const float* __restrict__ kg,
               const float* __restrict__ vg, const float* __restrict__ Lm,
               float* __restrict__ out)
{
    __shared__ float Qs[QT * LDP];
    __shared__ float Ks[KT * LDP];
    __shared__ float Vs[KT * LDP];
    __shared__ float Sb[QT * SBLD];
    __shared__ float mrow[QT], lrow[QT], arow[QT];
    __shared__ float LBuf[KT * 16];   // reused: q-rows first, then kv-rows per tile

    const int bh  = blockIdx.x;           // 0..63
    const int qt  = blockIdx.y;           // 0..31
    const int b   = bh >> 3;              // H = 8
    const int tid = threadIdx.x;
    const float scale = 0.08838834764831845f;  // 1/sqrt(128)

    // ---- load Q tile (32 x 128 floats, coalesced float4) ----
    const float* qbase = qg + ((size_t)bh * NSEQ + (size_t)qt * QT) * CD;
    #pragma unroll
    for (int it = 0; it < 4; ++it) {
        int f4  = tid + it * 256;         // 0..1023
        int row = f4 >> 5;                // 32 float4 per row
        int col = (f4 & 31) << 2;
        *(float4*)&Qs[row * LDP + col] = *(const float4*)(qbase + row * CD + col);
    }
    // L rows for the q-tile
    for (int t = tid; t < QT * 16; t += 256)
        LBuf[t] = Lm[((size_t)b * NSEQ + (size_t)qt * QT + (t >> 4)) * 16 + (t & 15)];
    if (tid < QT) { mrow[tid] = -1e30f; lrow[tid] = 0.0f; }
    __syncthreads();

    // ---- transform Q in LDS:  y = eta L^T eta x   (t = eta*x; z = L^T t; y = eta*z) ----
    for (int t = tid; t < QT * NV; t += 256) {
        int row = t / NV, vv = t - row * NV;
        float* p = &Qs[row * LDP + 8 + vv * 4];
        const float* Lr = &LBuf[row * 16];
        float t0 = p[0], t1 = -p[1], t2 = -p[2], t3 = -p[3];
        float z0 = Lr[0]*t0 + Lr[4]*t1 + Lr[8] *t2 + Lr[12]*t3;
        float z1 = Lr[1]*t0 + Lr[5]*t1 + Lr[9] *t2 + Lr[13]*t3;
        float z2 = Lr[2]*t0 + Lr[6]*t1 + Lr[10]*t2 + Lr[14]*t3;
        float z3 = Lr[3]*t0 + Lr[7]*t1 + Lr[11]*t2 + Lr[15]*t3;
        p[0] = z0; p[1] = -z1; p[2] = -z2; p[3] = -z3;
    }

    float acc[4][4];
    #pragma unroll
    for (int r = 0; r < 4; ++r)
        #pragma unroll
        for (int j = 0; j < 4; ++j) acc[r][j] = 0.0f;

    const int qgr = tid >> 4;   // 0..15 : score rows {2qgr, 2qgr+1}
    const int kgr = tid & 15;   // 0..15 : score cols {2kgr, 2kgr+1}
    const int cg  = tid & 31;   // 0..31 : PV channel group (4 floats)
    const int qq  = tid >> 5;   // 0..7  : PV rows {4qq..4qq+3}

    for (int kt2 = 0; kt2 < NSEQ / KT; ++kt2) {
        __syncthreads();  // protect Ks/Vs/Sb/LBuf from previous iteration readers
        const float* kbase = kg + ((size_t)bh * NSEQ + (size_t)kt2 * KT) * CD;
        const float* vbase = vg + ((size_t)bh * NSEQ + (size_t)kt2 * KT) * CD;
        #pragma unroll
        for (int it = 0; it < 4; ++it) {
            int f4  = tid + it * 256;
            int row = f4 >> 5;
            int col = (f4 & 31) << 2;
            *(float4*)&Ks[row * LDP + col] = *(const float4*)(kbase + row * CD + col);
            *(float4*)&Vs[row * LDP + col] = *(const float4*)(vbase + row * CD + col);
        }
        for (int t = tid; t < KT * 16; t += 256)
            LBuf[t] = Lm[((size_t)b * NSEQ + (size_t)kt2 * KT + (t >> 4)) * 16 + (t & 15)];
        __syncthreads();

        // ---- transform K (M = L^T eta) and V (M = eta L^T eta) in LDS ----
        for (int t = tid; t < KT * NV * 2; t += 256) {
            int which = (t >= KT * NV);
            int tt = which ? t - KT * NV : t;
            int row = tt / NV, vv = tt - row * NV;
            float* p = (which ? Vs : Ks) + row * LDP + 8 + vv * 4;
            const float* Lr = &LBuf[row * 16];
            float t0 = p[0], t1 = -p[1], t2 = -p[2], t3 = -p[3];
            float z0 = Lr[0]*t0 + Lr[4]*t1 + Lr[8] *t2 + Lr[12]*t3;
            float z1 = Lr[1]*t0 + Lr[5]*t1 + Lr[9] *t2 + Lr[13]*t3;
            float z2 = Lr[2]*t0 + Lr[6]*t1 + Lr[10]*t2 + Lr[14]*t3;
            float z3 = Lr[3]*t0 + Lr[7]*t1 + Lr[11]*t2 + Lr[15]*t3;
            if (which) { p[0] = z0; p[1] = -z1; p[2] = -z2; p[3] = -z3; }
            else       { p[0] = z0; p[1] =  z1; p[2] =  z2; p[3] =  z3; }
        }
        __syncthreads();

        // ---- scores: thread computes 2q x 2k sub-block of S (32x32) ----
        float sc00 = 0.f, sc01 = 0.f, sc10 = 0.f, sc11 = 0.f;
        #pragma unroll 8
        for (int c4 = 0; c4 < 32; ++c4) {
            float4 k0 = *(const float4*)&Ks[(kgr * 2 + 0) * LDP + c4 * 4];
            float4 k1 = *(const float4*)&Ks[(kgr * 2 + 1) * LDP + c4 * 4];
            float4 q0 = *(const float4*)&Qs[(qgr * 2 + 0) * LDP + c4 * 4];
            float4 q1 = *(const float4*)&Qs[(qgr * 2 + 1) * LDP + c4 * 4];
            sc00 += q0.x*k0.x + q0.y*k0.y + q0.z*k0.z + q0.w*k0.w;
            sc01 += q0.x*k1.x + q0.y*k1.y + q0.z*k1.z + q0.w*k1.w;
            sc10 += q1.x*k0.x + q1.y*k0.y + q1.z*k0.z + q1.w*k0.w;
            sc11 += q1.x*k1.x + q1.y*k1.y + q1.z*k1.z + q1.w*k1.w;
        }
        Sb[(qgr * 2 + 0) * SBLD + kgr * 2 + 0] = sc00 * scale;
        Sb[(qgr * 2 + 0) * SBLD + kgr * 2 + 1] = sc01 * scale;
        Sb[(qgr * 2 + 1) * SBLD + kgr * 2 + 0] = sc10 * scale;
        Sb[(qgr * 2 + 1) * SBLD + kgr * 2 + 1] = sc11 * scale;
        __syncthreads();

        // ---- online softmax stats (one thread per q row) ----
        if (tid < QT) {
            float mo = mrow[tid];
            float mx = mo;
            #pragma unroll 8
            for (int j = 0; j < KT; ++j) mx = fmaxf(mx, Sb[tid * SBLD + j]);
            float al = __expf(mo - mx);
            float s = 0.0f;
            #pragma unroll 8
            for (int j = 0; j < KT; ++j) {
                float pj = __expf(Sb[tid * SBLD + j] - mx);
                Sb[tid * SBLD + j] = pj;
                s += pj;
            }
            mrow[tid] = mx;
            lrow[tid] = al * lrow[tid] + s;
            arow[tid] = al;
        }
        __syncthreads();

        // ---- P.V : thread owns rows 4qq..4qq+3, channels 4cg..4cg+3 ----
        #pragma unroll
        for (int r = 0; r < 4; ++r) {
            float al = arow[qq * 4 + r];
            #pragma unroll
            for (int j = 0; j < 4; ++j) acc[r][j] *= al;
        }
        #pragma unroll 4
        for (int kk = 0; kk < KT; ++kk) {
            float4 vv4 = *(const float4*)&Vs[kk * LDP + cg * 4];
            #pragma unroll
            for (int r = 0; r < 4; ++r) {
                float pp = Sb[(qq * 4 + r) * SBLD + kk];
                acc[r][0] += pp * vv4.x;
                acc[r][1] += pp * vv4.y;
                acc[r][2] += pp * vv4.z;
                acc[r][3] += pp * vv4.w;
            }
        }
    }

    // ---- epilogue: normalize, apply final frame transform (M = L, row dot), store ----
    float* obase = out + ((size_t)bh * NSEQ + (size_t)qt * QT) * CD;
    #pragma unroll
    for (int r = 0; r < 4; ++r) {
        int row = qq * 4 + r;
        float inv_l = 1.0f / lrow[row];
        float o0 = acc[r][0] * inv_l, o1 = acc[r][1] * inv_l;
        float o2 = acc[r][2] * inv_l, o3 = acc[r][3] * inv_l;
        float4 res;
        if (cg >= 2) {
            const float* Lr = Lm + ((size_t)b * NSEQ + (size_t)qt * QT + row) * 16;
            res.x = Lr[0] *o0 + Lr[1] *o1 + Lr[2] *o2 + Lr[3] *o3;
            res.y = Lr[4] *o0 + Lr[5] *o1 + Lr[6] *o2 + Lr[7] *o3;
            res.z = Lr[8] *o0 + Lr[9] *o1 + Lr[10]*o2 + Lr[11]*o3;
            res.w = Lr[12]*o0 + Lr[13]*o1 + Lr[14]*o2 + Lr[15]*o3;
        } else {
            res.x = o0; res.y = o1; res.z = o2; res.w = o3;
        }
        *(float4*)(obase + row * CD + cg * 4) = res;
    }
}

extern "C" void kernel_launch(void* const* d_in, const int* in_sizes, int n_in,
                              void* d_out, int out_size, void* d_ws, size_t ws_size,
                              hipStream_t stream) {
    const float* q  = (const float*)d_in[0];
    const float* k  = (const float*)d_in[1];
    const float* v  = (const float*)d_in[2];
    const float* L  = (const float*)d_in[3];
    float* out = (float*)d_out;
    dim3 grid(BB * HH, NSEQ / QT);
    ipa_fused<<<grid, 256, 0, stream>>>(q, k, v, L, out);
}

// Round 2
// 407.817 us; speedup vs baseline: 3.5311x; 3.5311x over previous
//
#include <hip/hip_runtime.h>

typedef _Float16 f16;
typedef _Float16 f16x8 __attribute__((ext_vector_type(8)));
typedef _Float16 f16x4 __attribute__((ext_vector_type(4)));
typedef float    f32x4 __attribute__((ext_vector_type(4)));

#define NSEQ 1024
#define CD   128
#define QT   64      // queries per block (16 per wave)
#define KT   64      // keys per LDS tile
#define LQ   136     // f16 row stride for Qs/Ks: 272B = 17*16B, breaks bank alignment
#define LV   72      // f16 row stride for Vt (keys dim): 144B

// Vt column swizzle: key' = key ^ ((c>>2 & 15) << 2). Keeps aligned 4-key blocks
// contiguous (b64 frag reads) while spreading the channel->bank pattern.
__device__ __forceinline__ int vswz(int c, int key) { return key ^ (((c >> 2) & 15) << 2); }

__global__ __launch_bounds__(256, 2)
void ipa_mfma(const float* __restrict__ qg, const float* __restrict__ kg,
              const float* __restrict__ vg, const float* __restrict__ Lm,
              float* __restrict__ out)
{
    __shared__ f16   Qs[QT * LQ];     // 17408 B, transformed+scaled Q, [q][c]
    __shared__ f16   Ks[KT * LQ];     // 17408 B, transformed K, [key][c]
    __shared__ f16   Vt[CD * LV];     // 18432 B, transformed V^T, [c][key^swz]
    __shared__ float QL[QT * 16];     // 4096 B, L rows of the q-tile (kept for epilogue)
    __shared__ float KL[KT * 16];     // 4096 B, L rows of current k-tile

    const int tid  = threadIdx.x;
    const int bh   = blockIdx.x;      // 0..63
    const int b    = bh >> 3;         // H=8
    const int qt   = blockIdx.y;      // 0..15
    const int lane = tid & 63;
    const int w    = tid >> 6;        // wave 0..3 -> queries w*16..w*16+15
    const int lq   = lane & 15;
    const int quad = lane >> 4;

    const float* qbase  = qg + ((size_t)bh * NSEQ + (size_t)qt * QT) * CD;
    const float* Lqbase = Lm + ((size_t)b  * NSEQ + (size_t)qt * QT) * 16;

    for (int t = tid; t < QT * 16; t += 256) QL[t] = Lqbase[t];
    __syncthreads();

    // ---- stage Q: transform (M = eta L^T eta), pre-scale by 1/sqrt(C), f16 ----
    const float sc = 0.08838834764831845f;
    #pragma unroll
    for (int it = 0; it < 8; ++it) {
        int g = it * 256 + tid;           // 2048 float4-groups: [row 0..63][cg 0..31]
        int row = g >> 5, cg = g & 31;    // channels cg*4..cg*4+3; vector iff cg>=2
        float4 x = *(const float4*)(qbase + row * CD + cg * 4);
        const float* Lr = &QL[row * 16];
        float4 y = x;
        if (cg >= 2) {
            float t0 = x.x, t1 = -x.y, t2 = -x.z, t3 = -x.w;
            y.x =  (Lr[0]*t0 + Lr[4]*t1 + Lr[8] *t2 + Lr[12]*t3);
            y.y = -(Lr[1]*t0 + Lr[5]*t1 + Lr[9] *t2 + Lr[13]*t3);
            y.z = -(Lr[2]*t0 + Lr[6]*t1 + Lr[10]*t2 + Lr[14]*t3);
            y.w = -(Lr[3]*t0 + Lr[7]*t1 + Lr[11]*t2 + Lr[15]*t3);
        }
        f16x4 h = { (f16)(y.x*sc), (f16)(y.y*sc), (f16)(y.z*sc), (f16)(y.w*sc) };
        *(f16x4*)&Qs[row * LQ + cg * 4] = h;
    }
    __syncthreads();

    // ---- preload Q fragments (B-operand of S^T = K*Q^T), reused all k-tiles ----
    f16x8 qf[4];
    #pragma unroll
    for (int cs = 0; cs < 4; ++cs)
        qf[cs] = *(const f16x8*)&Qs[(w * 16 + lq) * LQ + cs * 32 + quad * 8];

    f32x4 oacc[8];   // O^T accumulator: oacc[cb] reg r <-> channel cb*16+quad*4+r, query lq
    #pragma unroll
    for (int cb = 0; cb < 8; ++cb) oacc[cb] = (f32x4){0.f, 0.f, 0.f, 0.f};
    float mrun = -1e30f, lrun = 0.0f;

    for (int kt0 = 0; kt0 < NSEQ; kt0 += KT) {
        const float* kbase  = kg + ((size_t)bh * NSEQ + kt0) * CD;
        const float* vbase  = vg + ((size_t)bh * NSEQ + kt0) * CD;
        const float* Lkbase = Lm + ((size_t)b  * NSEQ + kt0) * 16;

        __syncthreads();   // previous tile fully consumed
        for (int t = tid; t < KT * 16; t += 256) KL[t] = Lkbase[t];
        __syncthreads();   // KL ready

        // ---- stage K (M = L^T eta) and V^T (M = eta L^T eta) in f16 ----
        #pragma unroll
        for (int it = 0; it < 8; ++it) {
            int g = it * 256 + tid;
            int row = g >> 5, cg = g & 31;
            const float* Lr = &KL[row * 16];

            float4 xk = *(const float4*)(kbase + row * CD + cg * 4);
            float4 yk = xk;
            if (cg >= 2) {
                float t0 = xk.x, t1 = -xk.y, t2 = -xk.z, t3 = -xk.w;
                yk.x = Lr[0]*t0 + Lr[4]*t1 + Lr[8] *t2 + Lr[12]*t3;
                yk.y = Lr[1]*t0 + Lr[5]*t1 + Lr[9] *t2 + Lr[13]*t3;
                yk.z = Lr[2]*t0 + Lr[6]*t1 + Lr[10]*t2 + Lr[14]*t3;
                yk.w = Lr[3]*t0 + Lr[7]*t1 + Lr[11]*t2 + Lr[15]*t3;
            }
            f16x4 hk = { (f16)yk.x, (f16)yk.y, (f16)yk.z, (f16)yk.w };
            *(f16x4*)&Ks[row * LQ + cg * 4] = hk;

            float4 xv = *(const float4*)(vbase + row * CD + cg * 4);
            float4 yv = xv;
            if (cg >= 2) {
                float t0 = xv.x, t1 = -xv.y, t2 = -xv.z, t3 = -xv.w;
                yv.x =  (Lr[0]*t0 + Lr[4]*t1 + Lr[8] *t2 + Lr[12]*t3);
                yv.y = -(Lr[1]*t0 + Lr[5]*t1 + Lr[9] *t2 + Lr[13]*t3);
                yv.z = -(Lr[2]*t0 + Lr[6]*t1 + Lr[10]*t2 + Lr[14]*t3);
                yv.w = -(Lr[3]*t0 + Lr[7]*t1 + Lr[11]*t2 + Lr[15]*t3);
            }
            int kx = vswz(cg * 4, row);   // c>>2 == cg for all 4 channels of this group
            Vt[(cg * 4 + 0) * LV + kx] = (f16)yv.x;
            Vt[(cg * 4 + 1) * LV + kx] = (f16)yv.y;
            Vt[(cg * 4 + 2) * LV + kx] = (f16)yv.z;
            Vt[(cg * 4 + 3) * LV + kx] = (f16)yv.w;
        }
        __syncthreads();   // Ks/Vt ready

        // ---- 4 x 16-key MFMA steps ----
        #pragma unroll
        for (int k16 = 0; k16 < KT; k16 += 16) {
            f32x4 s = (f32x4){0.f, 0.f, 0.f, 0.f};
            #pragma unroll
            for (int cs = 0; cs < 4; ++cs) {
                f16x8 kf = *(const f16x8*)&Ks[(k16 + lq) * LQ + cs * 32 + quad * 8];
                s = __builtin_amdgcn_mfma_f32_16x16x32_f16(kf, qf[cs], s, 0, 0, 0);
            }
            // s reg r = S^T[key=k16+quad*4+r][q=lq]  (Q pre-scaled by 1/sqrt(C))
            float mx = fmaxf(fmaxf(s.x, s.y), fmaxf(s.z, s.w));
            mx = fmaxf(mx, __shfl_xor(mx, 16, 64));
            mx = fmaxf(mx, __shfl_xor(mx, 32, 64));
            float mnew  = fmaxf(mrun, mx);
            float alpha = __expf(mrun - mnew);
            float p0 = __expf(s.x - mnew), p1 = __expf(s.y - mnew);
            float p2 = __expf(s.z - mnew), p3 = __expf(s.w - mnew);
            float rs = (p0 + p1) + (p2 + p3);
            rs += __shfl_xor(rs, 16, 64);
            rs += __shfl_xor(rs, 32, 64);
            lrun = alpha * lrun + rs;
            mrun = mnew;
            f16x4 pf = { (f16)p0, (f16)p1, (f16)p2, (f16)p3 };  // B-frag of PV directly!
            #pragma unroll
            for (int cb = 0; cb < 8; ++cb) {
                int c  = cb * 16 + lq;
                int kx = vswz(c, k16 + quad * 4);
                f16x4 vf = *(const f16x4*)&Vt[c * LV + kx];
                oacc[cb] *= alpha;
                oacc[cb] = __builtin_amdgcn_mfma_f32_16x16x16f16(vf, pf, oacc[cb], 0, 0, 0);
            }
        }
    }

    // ---- epilogue: normalize, final frame transform (M = L, row-dot), store ----
    float invl = 1.0f / lrun;
    const int qrow = w * 16 + lq;
    const float* Lr = &QL[qrow * 16];
    float* obase = out + ((size_t)bh * NSEQ + (size_t)qt * QT + qrow) * CD;
    #pragma unroll
    for (int cb = 0; cb < 8; ++cb) {
        int c0 = cb * 16 + quad * 4;   // 4 consecutive channels = one 4-vector (or scalar quad)
        float o0 = oacc[cb].x * invl, o1 = oacc[cb].y * invl;
        float o2 = oacc[cb].z * invl, o3 = oacc[cb].w * invl;
        float4 r;
        if (c0 >= 8) {
            r.x = Lr[0] *o0 + Lr[1] *o1 + Lr[2] *o2 + Lr[3] *o3;
            r.y = Lr[4] *o0 + Lr[5] *o1 + Lr[6] *o2 + Lr[7] *o3;
            r.z = Lr[8] *o0 + Lr[9] *o1 + Lr[10]*o2 + Lr[11]*o3;
            r.w = Lr[12]*o0 + Lr[13]*o1 + Lr[14]*o2 + Lr[15]*o3;
        } else {
            r.x = o0; r.y = o1; r.z = o2; r.w = o3;
        }
        *(float4*)(obase + c0) = r;
    }
}

extern "C" void kernel_launch(void* const* d_in, const int* in_sizes, int n_in,
                              void* d_out, int out_size, void* d_ws, size_t ws_size,
                              hipStream_t stream) {
    const float* q = (const float*)d_in[0];
    const float* k = (const float*)d_in[1];
    const float* v = (const float*)d_in[2];
    const float* L = (const float*)d_in[3];
    float* o = (float*)d_out;
    dim3 grid(64, NSEQ / QT);   // 64 bh x 16 q-tiles
    ipa_mfma<<<grid, 256, 0, stream>>>(q, k, v, L, o);
}

// Round 3
// 212.384 us; speedup vs baseline: 6.7804x; 1.9202x over previous
//
#include <hip/hip_runtime.h>

typedef _Float16 f16;
typedef _Float16 f16x4 __attribute__((ext_vector_type(4)));
typedef _Float16 f16x8 __attribute__((ext_vector_type(8)));
typedef float    f32x4 __attribute__((ext_vector_type(4)));

#define NSEQ 1024
#define CD   128
#define QT   64
#define KT   64
#define LQ   136   // f16 row stride Ks/Qs (272 B): frag reads land 8 lanes/4-bank group (optimal b128)
#define LV   72    // f16 row stride Vt (144 B): same property for V-frags

// ---------------- kernel 1: Lorentz pre-transform K,V -> f16 in ws ----------------
__global__ __launch_bounds__(256)
void ipa_pre(const float* __restrict__ kg, const float* __restrict__ vg,
             const float* __restrict__ Lm, f16* __restrict__ kh, f16* __restrict__ vh)
{
    __shared__ float LL[64 * 16];
    const int bh = blockIdx.x, nt = blockIdx.y, b = bh >> 3, tid = threadIdx.x;
    const float* Lb = Lm + ((size_t)b * NSEQ + nt * 64) * 16;
    for (int t = tid; t < 64 * 16; t += 256) LL[t] = Lb[t];
    __syncthreads();
    const size_t base = ((size_t)bh * NSEQ + nt * 64) * CD;
    #pragma unroll
    for (int it = 0; it < 8; ++it) {
        int g = it * 256 + tid;
        int row = g >> 5, cg = g & 31;
        size_t idx = base + row * CD + cg * 4;
        const float* Lr = &LL[row * 16];
        float4 xk = *(const float4*)(kg + idx);
        float4 xv = *(const float4*)(vg + idx);
        float4 yk = xk, yv = xv;
        if (cg >= 2) {
            float t0 = xk.x, t1 = -xk.y, t2 = -xk.z, t3 = -xk.w;   // K: M = L^T eta
            yk.x = Lr[0]*t0 + Lr[4]*t1 + Lr[8] *t2 + Lr[12]*t3;
            yk.y = Lr[1]*t0 + Lr[5]*t1 + Lr[9] *t2 + Lr[13]*t3;
            yk.z = Lr[2]*t0 + Lr[6]*t1 + Lr[10]*t2 + Lr[14]*t3;
            yk.w = Lr[3]*t0 + Lr[7]*t1 + Lr[11]*t2 + Lr[15]*t3;
            t0 = xv.x; t1 = -xv.y; t2 = -xv.z; t3 = -xv.w;         // V: M = eta L^T eta
            yv.x =  (Lr[0]*t0 + Lr[4]*t1 + Lr[8] *t2 + Lr[12]*t3);
            yv.y = -(Lr[1]*t0 + Lr[5]*t1 + Lr[9] *t2 + Lr[13]*t3);
            yv.z = -(Lr[2]*t0 + Lr[6]*t1 + Lr[10]*t2 + Lr[14]*t3);
            yv.w = -(Lr[3]*t0 + Lr[7]*t1 + Lr[11]*t2 + Lr[15]*t3);
        }
        f16x4 hk = {(f16)yk.x, (f16)yk.y, (f16)yk.z, (f16)yk.w};
        f16x4 hv = {(f16)yv.x, (f16)yv.y, (f16)yv.z, (f16)yv.w};
        *(f16x4*)(kh + idx) = hk;
        *(f16x4*)(vh + idx) = hv;
    }
}

// ---------------- kernel 2: flash attention on pre-transformed f16 K/V ----------------
__global__ __launch_bounds__(256, 4)
void ipa_attn(const float* __restrict__ qg, const f16* __restrict__ kh,
              const f16* __restrict__ vh, const float* __restrict__ Lm,
              float* __restrict__ out)
{
    __shared__ __align__(16) f16 Ks[KT * LQ];   // 17408 B (also Q staging area)
    __shared__ __align__(16) f16 Vt[CD * LV];   // 18432 B (also L staging area)

    const int tid  = threadIdx.x;
    const int bh   = blockIdx.x, qt = blockIdx.y, b = bh >> 3;
    const int lane = tid & 63, w = tid >> 6, lq = lane & 15, quad = lane >> 4;
    const int q0   = qt * QT;

    // ---- stage L rows of q-tile into (aliased) LDS, transform Q, preload frags ----
    float* LL = (float*)Vt;
    const float* Lqb = Lm + ((size_t)b * NSEQ + q0) * 16;
    for (int t = tid; t < 64 * 16; t += 256) LL[t] = Lqb[t];
    __syncthreads();

    const float sc = 0.08838834764831845f;   // 1/sqrt(128)
    const size_t qbase = ((size_t)bh * NSEQ + q0) * CD;
    #pragma unroll
    for (int it = 0; it < 8; ++it) {
        int g = it * 256 + tid;
        int row = g >> 5, cg = g & 31;
        float4 x = *(const float4*)(qg + qbase + row * CD + cg * 4);
        const float* Lr = &LL[row * 16];
        float4 y = x;
        if (cg >= 2) {                        // Q: M = eta L^T eta
            float t0 = x.x, t1 = -x.y, t2 = -x.z, t3 = -x.w;
            y.x =  (Lr[0]*t0 + Lr[4]*t1 + Lr[8] *t2 + Lr[12]*t3);
            y.y = -(Lr[1]*t0 + Lr[5]*t1 + Lr[9] *t2 + Lr[13]*t3);
            y.z = -(Lr[2]*t0 + Lr[6]*t1 + Lr[10]*t2 + Lr[14]*t3);
            y.w = -(Lr[3]*t0 + Lr[7]*t1 + Lr[11]*t2 + Lr[15]*t3);
        }
        f16x4 h = {(f16)(y.x*sc), (f16)(y.y*sc), (f16)(y.z*sc), (f16)(y.w*sc)};
        *(f16x4*)&Ks[row * LQ + cg * 4] = h;   // Qs aliases Ks
    }
    __syncthreads();

    f16x8 qf[4];
    #pragma unroll
    for (int cs = 0; cs < 4; ++cs)
        qf[cs] = *(const f16x8*)&Ks[(w * 16 + lq) * LQ + cs * 32 + quad * 8];

    f32x4 oacc[8];
    #pragma unroll
    for (int cb = 0; cb < 8; ++cb) oacc[cb] = (f32x4){0.f, 0.f, 0.f, 0.f};
    float mrun = -1e30f, lrun = 0.0f;

    const size_t kvbase = (size_t)bh * NSEQ * CD;

    for (int kt0 = 0; kt0 < NSEQ; kt0 += KT) {
        __syncthreads();   // previous tile consumed (also guards Q/L staging areas)

        // K stage, permuted rows: LDS row m=16h+4a+r (per 32-group) <- key 8a+4h+r.
        // Makes QK^T output regs land exactly in PV B-frag order (keys quad*8+j).
        #pragma unroll
        for (int it = 0; it < 4; ++it) {
            int ch = it * 256 + tid;
            int m = ch >> 4, c0 = (ch & 15) * 8;
            int gg = m >> 5, mm = m & 31;
            int h = (mm >> 4) & 1, a = (mm >> 2) & 3, r = mm & 3;
            int kap = gg * 32 + 8 * a + 4 * h + r;
            f16x8 kv8 = *(const f16x8*)(kh + kvbase + (size_t)(kt0 + kap) * CD + c0);
            *(f16x8*)&Ks[m * LQ + c0] = kv8;
        }
        // V stage transposed: per-wave-uniform c0 -> stride-1 key stores (conflict-free)
        {
            int key = tid & 63, wv = tid >> 6;
            #pragma unroll
            for (int j = 0; j < 4; ++j) {
                int c0 = wv * 32 + j * 8;
                f16x8 vv = *(const f16x8*)(vh + kvbase + (size_t)(kt0 + key) * CD + c0);
                #pragma unroll
                for (int i = 0; i < 8; ++i) Vt[(c0 + i) * LV + key] = vv[i];
            }
        }
        __syncthreads();

        #pragma unroll
        for (int g2 = 0; g2 < 2; ++g2) {    // two 32-key steps
            f32x4 s0 = (f32x4){0.f,0.f,0.f,0.f}, s1 = (f32x4){0.f,0.f,0.f,0.f};
            #pragma unroll
            for (int cs = 0; cs < 4; ++cs) {
                f16x8 ka = *(const f16x8*)&Ks[(g2 * 32 + lq)      * LQ + cs * 32 + quad * 8];
                f16x8 kb = *(const f16x8*)&Ks[(g2 * 32 + 16 + lq) * LQ + cs * 32 + quad * 8];
                s0 = __builtin_amdgcn_mfma_f32_16x16x32_f16(ka, qf[cs], s0, 0, 0, 0);
                s1 = __builtin_amdgcn_mfma_f32_16x16x32_f16(kb, qf[cs], s1, 0, 0, 0);
            }
            // s0 reg r -> key g2*32 + 8*quad + r ; s1 reg r -> key g2*32 + 8*quad + 4 + r
            float mx = fmaxf(fmaxf(fmaxf(s0.x,s0.y), fmaxf(s0.z,s0.w)),
                             fmaxf(fmaxf(s1.x,s1.y), fmaxf(s1.z,s1.w)));
            mx = fmaxf(mx, __shfl_xor(mx, 16, 64));
            mx = fmaxf(mx, __shfl_xor(mx, 32, 64));
            float mnew  = fmaxf(mrun, mx);
            float alpha = __expf(mrun - mnew);
            float p0=__expf(s0.x-mnew), p1=__expf(s0.y-mnew), p2=__expf(s0.z-mnew), p3=__expf(s0.w-mnew);
            float p4=__expf(s1.x-mnew), p5=__expf(s1.y-mnew), p6=__expf(s1.z-mnew), p7=__expf(s1.w-mnew);
            float rs = ((p0+p1)+(p2+p3)) + ((p4+p5)+(p6+p7));
            rs += __shfl_xor(rs, 16, 64);
            rs += __shfl_xor(rs, 32, 64);
            lrun = alpha * lrun + rs;
            mrun = mnew;
            f16x8 pf = {(f16)p0,(f16)p1,(f16)p2,(f16)p3,(f16)p4,(f16)p5,(f16)p6,(f16)p7};
            #pragma unroll
            for (int cb = 0; cb < 8; ++cb) {
                f16x8 vf = *(const f16x8*)&Vt[(cb * 16 + lq) * LV + g2 * 32 + quad * 8];
                oacc[cb] *= alpha;
                oacc[cb] = __builtin_amdgcn_mfma_f32_16x16x32_f16(vf, pf, oacc[cb], 0, 0, 0);
            }
        }
    }

    // ---- epilogue: normalize, final frame transform (M = L, row-dot), store ----
    float invl = 1.0f / lrun;
    const int qrow = w * 16 + lq;
    const float* Lr = Lm + ((size_t)b * NSEQ + q0 + qrow) * 16;
    float* ob = out + ((size_t)bh * NSEQ + q0 + qrow) * CD;
    #pragma unroll
    for (int cb = 0; cb < 8; ++cb) {
        int c0 = cb * 16 + quad * 4;
        float o0 = oacc[cb].x*invl, o1 = oacc[cb].y*invl, o2 = oacc[cb].z*invl, o3 = oacc[cb].w*invl;
        float4 r;
        if (c0 >= 8) {
            r.x = Lr[0] *o0 + Lr[1] *o1 + Lr[2] *o2 + Lr[3] *o3;
            r.y = Lr[4] *o0 + Lr[5] *o1 + Lr[6] *o2 + Lr[7] *o3;
            r.z = Lr[8] *o0 + Lr[9] *o1 + Lr[10]*o2 + Lr[11]*o3;
            r.w = Lr[12]*o0 + Lr[13]*o1 + Lr[14]*o2 + Lr[15]*o3;
        } else {
            r.x = o0; r.y = o1; r.z = o2; r.w = o3;
        }
        *(float4*)(ob + c0) = r;
    }
}

extern "C" void kernel_launch(void* const* d_in, const int* in_sizes, int n_in,
                              void* d_out, int out_size, void* d_ws, size_t ws_size,
                              hipStream_t stream) {
    const float* q = (const float*)d_in[0];
    const float* k = (const float*)d_in[1];
    const float* v = (const float*)d_in[2];
    const float* L = (const float*)d_in[3];
    float* o = (float*)d_out;
    f16* kh = (f16*)d_ws;                                 // 16 MB
    f16* vh = kh + (size_t)64 * NSEQ * CD;                // 16 MB
    dim3 grid(64, NSEQ / KT);
    ipa_pre<<<grid, 256, 0, stream>>>(k, v, L, kh, vh);
    dim3 grid2(64, NSEQ / QT);
    ipa_attn<<<grid2, 256, 0, stream>>>(q, kh, vh, L, o);
}

// Round 4
// 211.547 us; speedup vs baseline: 6.8072x; 1.0040x over previous
//
#include <hip/hip_runtime.h>

typedef _Float16 f16;
typedef _Float16 f16x4 __attribute__((ext_vector_type(4)));
typedef _Float16 f16x8 __attribute__((ext_vector_type(8)));
typedef float    f32x4 __attribute__((ext_vector_type(4)));

#define NSEQ 1024
#define CD   128
#define QT   128   // queries per block: 4 waves x 32
#define KT   128   // keys per LDS tile

// ---------------- kernel 1: Lorentz pre-transform Q,K,V -> f16 ----------------
__global__ __launch_bounds__(256)
void ipa_pre(const float* __restrict__ qg, const float* __restrict__ kg,
             const float* __restrict__ vg, const float* __restrict__ Lm,
             f16* __restrict__ qh, f16* __restrict__ kh, f16* __restrict__ vh)
{
    __shared__ float LL[64 * 16];
    const int bh = blockIdx.x, nt = blockIdx.y, b = bh >> 3, tid = threadIdx.x;
    const float* Lb = Lm + ((size_t)b * NSEQ + nt * 64) * 16;
    for (int t = tid; t < 64 * 16; t += 256) LL[t] = Lb[t];
    __syncthreads();
    const size_t base = ((size_t)bh * NSEQ + nt * 64) * CD;
    const float sc = 0.08838834764831845f;   // 1/sqrt(128)
    #pragma unroll
    for (int it = 0; it < 8; ++it) {
        int g = it * 256 + tid;
        int row = g >> 5, cg = g & 31;
        size_t idx = base + row * CD + cg * 4;
        const float* Lr = &LL[row * 16];
        float4 xq = *(const float4*)(qg + idx);
        float4 xk = *(const float4*)(kg + idx);
        float4 xv = *(const float4*)(vg + idx);
        float4 yq = xq, yk = xk, yv = xv;
        if (cg >= 2) {
            float t0 = xk.x, t1 = -xk.y, t2 = -xk.z, t3 = -xk.w;   // K: M = L^T eta
            yk.x = Lr[0]*t0 + Lr[4]*t1 + Lr[8] *t2 + Lr[12]*t3;
            yk.y = Lr[1]*t0 + Lr[5]*t1 + Lr[9] *t2 + Lr[13]*t3;
            yk.z = Lr[2]*t0 + Lr[6]*t1 + Lr[10]*t2 + Lr[14]*t3;
            yk.w = Lr[3]*t0 + Lr[7]*t1 + Lr[11]*t2 + Lr[15]*t3;
            t0 = xv.x; t1 = -xv.y; t2 = -xv.z; t3 = -xv.w;         // V: M = eta L^T eta
            yv.x =  (Lr[0]*t0 + Lr[4]*t1 + Lr[8] *t2 + Lr[12]*t3);
            yv.y = -(Lr[1]*t0 + Lr[5]*t1 + Lr[9] *t2 + Lr[13]*t3);
            yv.z = -(Lr[2]*t0 + Lr[6]*t1 + Lr[10]*t2 + Lr[14]*t3);
            yv.w = -(Lr[3]*t0 + Lr[7]*t1 + Lr[11]*t2 + Lr[15]*t3);
            t0 = xq.x; t1 = -xq.y; t2 = -xq.z; t3 = -xq.w;         // Q: M = eta L^T eta
            yq.x =  (Lr[0]*t0 + Lr[4]*t1 + Lr[8] *t2 + Lr[12]*t3);
            yq.y = -(Lr[1]*t0 + Lr[5]*t1 + Lr[9] *t2 + Lr[13]*t3);
            yq.z = -(Lr[2]*t0 + Lr[6]*t1 + Lr[10]*t2 + Lr[14]*t3);
            yq.w = -(Lr[3]*t0 + Lr[7]*t1 + Lr[11]*t2 + Lr[15]*t3);
        }
        f16x4 hq = {(f16)(yq.x*sc), (f16)(yq.y*sc), (f16)(yq.z*sc), (f16)(yq.w*sc)};
        f16x4 hk = {(f16)yk.x, (f16)yk.y, (f16)yk.z, (f16)yk.w};
        f16x4 hv = {(f16)yv.x, (f16)yv.y, (f16)yv.z, (f16)yv.w};
        *(f16x4*)(qh + idx) = hq;
        *(f16x4*)(kh + idx) = hk;
        *(f16x4*)(vh + idx) = hv;
    }
}

// ---------------- kernel 2: flash attention, 32 queries/wave ----------------
__global__ __launch_bounds__(256, 2)
void ipa_attn(const f16* __restrict__ qh, const f16* __restrict__ kh,
              const f16* __restrict__ vh, const float* __restrict__ Lm,
              float* __restrict__ out)
{
    // XOR-swizzled, power-of-2 strides; 64 KB total.
    __shared__ __align__(16) f16 Ks[KT * CD];   // [row m][c ^ ((m&7)<<3)]
    __shared__ __align__(16) f16 Vt[CD * KT];   // [c][key ^ ((c&7)<<3)]

    const int tid  = threadIdx.x;
    const int bh   = blockIdx.x, qt = blockIdx.y, b = bh >> 3;
    const int lane = tid & 63, w = tid >> 6, lq = lane & 15, quad = lane >> 4;
    const int q0   = qt * QT;
    const size_t kvbase = (size_t)bh * NSEQ * CD;

    // ---- Q fragments straight from pre-transformed global ----
    f16x8 qf[2][4];
    #pragma unroll
    for (int u = 0; u < 2; ++u)
        #pragma unroll
        for (int cs = 0; cs < 4; ++cs)
            qf[u][cs] = *(const f16x8*)(qh + kvbase + (size_t)(q0 + w*32 + u*16 + lq) * CD
                                           + cs * 32 + quad * 8);

    f32x4 oacc[2][8];
    #pragma unroll
    for (int u = 0; u < 2; ++u)
        #pragma unroll
        for (int cb = 0; cb < 8; ++cb) oacc[u][cb] = (f32x4){0.f, 0.f, 0.f, 0.f};
    float mrun[2] = {-1e30f, -1e30f}, lrun[2] = {0.f, 0.f};

    for (int kt0 = 0; kt0 < NSEQ; kt0 += KT) {
        __syncthreads();   // previous tile consumed

        // K stage, row-permuted (within 32-key groups) so QK output regs form PV B-frags
        #pragma unroll
        for (int it = 0; it < 8; ++it) {
            int g = it * 256 + tid;
            int m = g >> 4, c0 = (g & 15) * 8;
            int mm = m & 31, h = (mm >> 4) & 1, a = (mm >> 2) & 3, r = mm & 3;
            int kap = (m & ~31) | (8 * a + 4 * h + r);
            f16x8 kv = *(const f16x8*)(kh + kvbase + (size_t)(kt0 + kap) * CD + c0);
            *(f16x8*)&Ks[m * CD + (c0 ^ ((m & 7) << 3))] = kv;
        }
        // V stage transposed: lanes span consecutive keys -> conflict-free b16 stores
        #pragma unroll
        for (int j = 0; j < 8; ++j) {
            int key = (tid & 63) + (j & 1) * 64;
            int c0  = (tid >> 6) * 32 + (j >> 1) * 8;
            f16x8 vv = *(const f16x8*)(vh + kvbase + (size_t)(kt0 + key) * CD + c0);
            #pragma unroll
            for (int i = 0; i < 8; ++i)
                Vt[(c0 + i) * KT + (key ^ (i << 3))] = vv[i];   // (c0+i)&7 == i
        }
        __syncthreads();

        #pragma unroll
        for (int half = 0; half < 2; ++half) {
            const int kb = half * 64;
            f32x4 s[2][4];
            #pragma unroll
            for (int u = 0; u < 2; ++u)
                #pragma unroll
                for (int g = 0; g < 4; ++g) s[u][g] = (f32x4){0.f, 0.f, 0.f, 0.f};
            #pragma unroll
            for (int g = 0; g < 4; ++g) {
                int R = kb + g * 16 + lq;
                #pragma unroll
                for (int cs = 0; cs < 4; ++cs) {
                    f16x8 ka = *(const f16x8*)&Ks[R * CD + ((cs*32 + quad*8) ^ ((R & 7) << 3))];
                    s[0][g] = __builtin_amdgcn_mfma_f32_16x16x32_f16(ka, qf[0][cs], s[0][g], 0, 0, 0);
                    s[1][g] = __builtin_amdgcn_mfma_f32_16x16x32_f16(ka, qf[1][cs], s[1][g], 0, 0, 0);
                }
            }
            // deferred online softmax over 64 keys (16 scores/lane per u)
            f16x8 pf[2][2];
            float alpha[2];
            #pragma unroll
            for (int u = 0; u < 2; ++u) {
                float mx = -1e30f;
                #pragma unroll
                for (int g = 0; g < 4; ++g)
                    mx = fmaxf(mx, fmaxf(fmaxf(s[u][g].x, s[u][g].y), fmaxf(s[u][g].z, s[u][g].w)));
                mx = fmaxf(mx, __shfl_xor(mx, 16, 64));
                mx = fmaxf(mx, __shfl_xor(mx, 32, 64));
                float mnew = fmaxf(mrun[u], mx);
                alpha[u] = __expf(mrun[u] - mnew);
                float rs = 0.f;
                float p[16];
                #pragma unroll
                for (int g = 0; g < 4; ++g) {
                    p[g*4+0] = __expf(s[u][g].x - mnew);
                    p[g*4+1] = __expf(s[u][g].y - mnew);
                    p[g*4+2] = __expf(s[u][g].z - mnew);
                    p[g*4+3] = __expf(s[u][g].w - mnew);
                    rs += (p[g*4+0] + p[g*4+1]) + (p[g*4+2] + p[g*4+3]);
                }
                rs += __shfl_xor(rs, 16, 64);
                rs += __shfl_xor(rs, 32, 64);
                lrun[u] = alpha[u] * lrun[u] + rs;
                mrun[u] = mnew;
                pf[u][0] = (f16x8){(f16)p[0],(f16)p[1],(f16)p[2],(f16)p[3],(f16)p[4],(f16)p[5],(f16)p[6],(f16)p[7]};
                pf[u][1] = (f16x8){(f16)p[8],(f16)p[9],(f16)p[10],(f16)p[11],(f16)p[12],(f16)p[13],(f16)p[14],(f16)p[15]};
            }
            #pragma unroll
            for (int u = 0; u < 2; ++u)
                #pragma unroll
                for (int cb = 0; cb < 8; ++cb) oacc[u][cb] *= alpha[u];
            #pragma unroll
            for (int p2 = 0; p2 < 2; ++p2) {
                int kbase = kb + p2 * 32 + quad * 8;   // true-key base of this B-frag
                #pragma unroll
                for (int cb = 0; cb < 8; ++cb) {
                    int c = cb * 16 + lq;
                    f16x8 vf = *(const f16x8*)&Vt[c * KT + (kbase ^ ((c & 7) << 3))];
                    oacc[0][cb] = __builtin_amdgcn_mfma_f32_16x16x32_f16(vf, pf[0][p2], oacc[0][cb], 0, 0, 0);
                    oacc[1][cb] = __builtin_amdgcn_mfma_f32_16x16x32_f16(vf, pf[1][p2], oacc[1][cb], 0, 0, 0);
                }
            }
        }
    }

    // ---- epilogue: normalize, final frame transform (M = L), store ----
    #pragma unroll
    for (int u = 0; u < 2; ++u) {
        const int qrow = w * 32 + u * 16 + lq;
        float invl = 1.0f / lrun[u];
        const float* Lr = Lm + ((size_t)b * NSEQ + q0 + qrow) * 16;
        float* ob = out + ((size_t)bh * NSEQ + q0 + qrow) * CD;
        #pragma unroll
        for (int cb = 0; cb < 8; ++cb) {
            int c0 = cb * 16 + quad * 4;
            float o0 = oacc[u][cb].x*invl, o1 = oacc[u][cb].y*invl;
            float o2 = oacc[u][cb].z*invl, o3 = oacc[u][cb].w*invl;
            float4 r;
            if (c0 >= 8) {
                r.x = Lr[0] *o0 + Lr[1] *o1 + Lr[2] *o2 + Lr[3] *o3;
                r.y = Lr[4] *o0 + Lr[5] *o1 + Lr[6] *o2 + Lr[7] *o3;
                r.z = Lr[8] *o0 + Lr[9] *o1 + Lr[10]*o2 + Lr[11]*o3;
                r.w = Lr[12]*o0 + Lr[13]*o1 + Lr[14]*o2 + Lr[15]*o3;
            } else {
                r.x = o0; r.y = o1; r.z = o2; r.w = o3;
            }
            *(float4*)(ob + c0) = r;
        }
    }
}

extern "C" void kernel_launch(void* const* d_in, const int* in_sizes, int n_in,
                              void* d_out, int out_size, void* d_ws, size_t ws_size,
                              hipStream_t stream) {
    const float* q = (const float*)d_in[0];
    const float* k = (const float*)d_in[1];
    const float* v = (const float*)d_in[2];
    const float* L = (const float*)d_in[3];
    float* o = (float*)d_out;
    const size_t tot = (size_t)64 * NSEQ * CD;     // 8.39M elements per tensor
    f16* qh = (f16*)d_ws;
    f16* kh = qh + tot;
    f16* vh = kh + tot;                            // 3 x 16.78 MB = 50.3 MB
    dim3 grid1(64, NSEQ / 64);
    ipa_pre<<<grid1, 256, 0, stream>>>(q, k, v, L, qh, kh, vh);
    dim3 grid2(64, NSEQ / QT);
    ipa_attn<<<grid2, 256, 0, stream>>>(qh, kh, vh, L, o);
}

// Round 5
// 194.019 us; speedup vs baseline: 7.4222x; 1.0903x over previous
//
#include <hip/hip_runtime.h>
#include <math.h>

typedef _Float16 f16;
typedef _Float16 f16x4 __attribute__((ext_vector_type(4)));
typedef _Float16 f16x8 __attribute__((ext_vector_type(8)));
typedef float    f32x4 __attribute__((ext_vector_type(4)));

#define NSEQ 1024
#define CD   128
#define LT   136   // pre-kernel LDS f16 row stride (272 B = 17*16 B, keeps b128 alignment)

// khs: [bh][g16 0..63][cs 0..3][lane 0..63][j 0..7]   (131072 f16 per bh)
//   value = Ktr[key = (g16>>1)*32 + 8*(lq>>2) + 4*(g16&1) + (lq&3)][c = cs*32+quad*8+j]
// vhs: [bh][k32 0..31][cb 0..7][lane 0..63][j 0..7]
//   value = Vtr[key = k32*32 + quad*8 + j][c = cb*16 + lq]
// Both are exact MFMA fragment order: a wave's frag load = base + lane*16B (coalesced 1KB).

__global__ __launch_bounds__(256)
void ipa_pre(const float* __restrict__ kg, const float* __restrict__ vg,
             const float* __restrict__ Lm, f16* __restrict__ khs, f16* __restrict__ vhs)
{
    __shared__ float LL[64 * 16];
    __shared__ __align__(16) f16 Kt[64 * LT];
    __shared__ __align__(16) f16 Vt[64 * LT];
    const int bx = blockIdx.x, nt = blockIdx.y, tid = threadIdx.x;
    const int bh = ((bx & 7) << 3) | (bx >> 3);   // XCD x <-> bh 8x..8x+7 (matches attn)
    const int b  = bh >> 3;
    const float* Lb = Lm + ((size_t)b * NSEQ + nt * 64) * 16;
    for (int t = tid; t < 64 * 16; t += 256) LL[t] = Lb[t];
    __syncthreads();

    const size_t base = ((size_t)bh * NSEQ + nt * 64) * CD;
    #pragma unroll
    for (int it = 0; it < 8; ++it) {
        int g = it * 256 + tid;
        int row = g >> 5, cg = g & 31;
        size_t idx = base + row * CD + cg * 4;
        const float* Lr = &LL[row * 16];
        float4 xk = *(const float4*)(kg + idx);
        float4 xv = *(const float4*)(vg + idx);
        float4 yk = xk, yv = xv;
        if (cg >= 2) {
            float t0 = xk.x, t1 = -xk.y, t2 = -xk.z, t3 = -xk.w;   // K: M = L^T eta
            yk.x = Lr[0]*t0 + Lr[4]*t1 + Lr[8] *t2 + Lr[12]*t3;
            yk.y = Lr[1]*t0 + Lr[5]*t1 + Lr[9] *t2 + Lr[13]*t3;
            yk.z = Lr[2]*t0 + Lr[6]*t1 + Lr[10]*t2 + Lr[14]*t3;
            yk.w = Lr[3]*t0 + Lr[7]*t1 + Lr[11]*t2 + Lr[15]*t3;
            t0 = xv.x; t1 = -xv.y; t2 = -xv.z; t3 = -xv.w;         // V: M = eta L^T eta
            yv.x =  (Lr[0]*t0 + Lr[4]*t1 + Lr[8] *t2 + Lr[12]*t3);
            yv.y = -(Lr[1]*t0 + Lr[5]*t1 + Lr[9] *t2 + Lr[13]*t3);
            yv.z = -(Lr[2]*t0 + Lr[6]*t1 + Lr[10]*t2 + Lr[14]*t3);
            yv.w = -(Lr[3]*t0 + Lr[7]*t1 + Lr[11]*t2 + Lr[15]*t3);
        }
        f16x4 hk = {(f16)yk.x, (f16)yk.y, (f16)yk.z, (f16)yk.w};
        f16x4 hv = {(f16)yv.x, (f16)yv.y, (f16)yv.z, (f16)yv.w};
        *(f16x4*)&Kt[row * LT + cg * 4] = hk;
        *(f16x4*)&Vt[row * LT + cg * 4] = hv;
    }
    __syncthreads();

    // staged K out (b128 LDS read -> fully coalesced global store)
    f16* kout = khs + (size_t)bh * 131072 + (size_t)nt * 4 * 4 * 512;
    #pragma unroll
    for (int it = 0; it < 4; ++it) {
        int slot = it * 256 + tid;                 // (g16l, cs, L)
        int g16l = slot >> 8, cs = (slot >> 6) & 3, L = slot & 63;
        int lq = L & 15, quad = L >> 4;
        int keyl = ((g16l >> 1) << 5) + ((lq >> 2) << 3) + ((g16l & 1) << 2) + (lq & 3);
        f16x8 kv = *(const f16x8*)&Kt[keyl * LT + cs * 32 + quad * 8];
        *(f16x8*)(kout + (g16l * 4 + cs) * 512 + L * 8) = kv;
    }
    // staged V^T out (scalar LDS column reads -> coalesced global store)
    f16* vout = vhs + (size_t)bh * 131072 + (size_t)nt * 2 * 8 * 512;
    #pragma unroll
    for (int it = 0; it < 4; ++it) {
        int slot = it * 256 + tid;                 // (k32l, cb, L)
        int k32l = slot >> 9, cb = (slot >> 6) & 7, L = slot & 63;
        int lq = L & 15, quad = L >> 4;
        int c = cb * 16 + lq;
        f16x8 o;
        #pragma unroll
        for (int j = 0; j < 8; ++j)
            o[j] = Vt[(k32l * 32 + quad * 8 + j) * LT + c];
        *(f16x8*)(vout + (k32l * 8 + cb) * 512 + L * 8) = o;
    }
}

// ---------------- attention: no LDS, no barriers, pure streaming ----------------
__global__ __launch_bounds__(128, 2)
void ipa_attn(const float* __restrict__ qg, const f16* __restrict__ khs,
              const f16* __restrict__ vhs, const float* __restrict__ Lm,
              float* __restrict__ out)
{
    const int n = blockIdx.x;
    const int bh = ((n & 7) << 3) | ((n >> 3) & 7);   // XCD x (n%8) handles bh 8x..8x+7
    const int b  = bh >> 3;
    const int tid = threadIdx.x;
    const int w = tid >> 6, lane = tid & 63, lq = lane & 15, quad = lane >> 4;
    const int qw = (n >> 6) * 2 + w;                  // 0..31
    const int q0 = qw * 32;
    const f16* kbh = khs + (size_t)bh * 131072;
    const f16* vbh = vhs + (size_t)bh * 131072;
    const float sc2 = 0.12751744154226873f;           // (1/sqrt(128)) * log2(e)

    // ---- Q: load fp32, transform (M = eta L^T eta) per-lane, scale, make frags ----
    f16x8 qf[2][4];
    #pragma unroll
    for (int u = 0; u < 2; ++u) {
        int qrow = q0 + u * 16 + lq;
        const float* Lr = Lm + ((size_t)b * NSEQ + qrow) * 16;
        const float* qp = qg + ((size_t)bh * NSEQ + qrow) * CD;
        float Lv[16];
        #pragma unroll
        for (int i = 0; i < 4; ++i) *(float4*)&Lv[i*4] = *(const float4*)(Lr + i*4);
        #pragma unroll
        for (int cs = 0; cs < 4; ++cs) {
            int c0 = cs * 32 + quad * 8;
            float4 x0 = *(const float4*)(qp + c0);
            float4 x1 = *(const float4*)(qp + c0 + 4);
            if (c0 >= 8) {
                float t0 = x0.x, t1 = -x0.y, t2 = -x0.z, t3 = -x0.w;
                float4 y;
                y.x =  (Lv[0]*t0 + Lv[4]*t1 + Lv[8] *t2 + Lv[12]*t3);
                y.y = -(Lv[1]*t0 + Lv[5]*t1 + Lv[9] *t2 + Lv[13]*t3);
                y.z = -(Lv[2]*t0 + Lv[6]*t1 + Lv[10]*t2 + Lv[14]*t3);
                y.w = -(Lv[3]*t0 + Lv[7]*t1 + Lv[11]*t2 + Lv[15]*t3);
                x0 = y;
                t0 = x1.x; t1 = -x1.y; t2 = -x1.z; t3 = -x1.w;
                y.x =  (Lv[0]*t0 + Lv[4]*t1 + Lv[8] *t2 + Lv[12]*t3);
                y.y = -(Lv[1]*t0 + Lv[5]*t1 + Lv[9] *t2 + Lv[13]*t3);
                y.z = -(Lv[2]*t0 + Lv[6]*t1 + Lv[10]*t2 + Lv[14]*t3);
                y.w = -(Lv[3]*t0 + Lv[7]*t1 + Lv[11]*t2 + Lv[15]*t3);
                x1 = y;
            }
            qf[u][cs] = (f16x8){(f16)(x0.x*sc2), (f16)(x0.y*sc2), (f16)(x0.z*sc2), (f16)(x0.w*sc2),
                                (f16)(x1.x*sc2), (f16)(x1.y*sc2), (f16)(x1.z*sc2), (f16)(x1.w*sc2)};
        }
    }

    f32x4 oacc[2][8];
    #pragma unroll
    for (int u = 0; u < 2; ++u)
        #pragma unroll
        for (int cb = 0; cb < 8; ++cb) oacc[u][cb] = (f32x4){0.f, 0.f, 0.f, 0.f};
    float mrun[2] = {-1e30f, -1e30f}, lrun[2] = {0.f, 0.f};

    for (int it = 0; it < 16; ++it) {                 // 64 keys per iteration
        const f16* kp = kbh + (size_t)it * 16 * 512;
        f16x8 kf[4][4];
        #pragma unroll
        for (int g = 0; g < 4; ++g)
            #pragma unroll
            for (int cs = 0; cs < 4; ++cs)
                kf[g][cs] = *(const f16x8*)(kp + (g * 4 + cs) * 512 + lane * 8);

        f32x4 s[2][4];
        #pragma unroll
        for (int u = 0; u < 2; ++u)
            #pragma unroll
            for (int g = 0; g < 4; ++g) s[u][g] = (f32x4){0.f, 0.f, 0.f, 0.f};
        #pragma unroll
        for (int g = 0; g < 4; ++g)
            #pragma unroll
            for (int cs = 0; cs < 4; ++cs) {
                s[0][g] = __builtin_amdgcn_mfma_f32_16x16x32_f16(kf[g][cs], qf[0][cs], s[0][g], 0, 0, 0);
                s[1][g] = __builtin_amdgcn_mfma_f32_16x16x32_f16(kf[g][cs], qf[1][cs], s[1][g], 0, 0, 0);
            }

        const f16* vp = vbh + (size_t)it * 2 * 8 * 512;
        f16x8 vf[2][8];
        #pragma unroll
        for (int k2 = 0; k2 < 2; ++k2)
            #pragma unroll
            for (int cb = 0; cb < 8; ++cb)
                vf[k2][cb] = *(const f16x8*)(vp + (k2 * 8 + cb) * 512 + lane * 8);

        // exp2-domain online softmax (scores already scaled by log2e)
        f16x8 pf[2][2];
        float alpha[2];
        #pragma unroll
        for (int u = 0; u < 2; ++u) {
            float mx = -1e30f;
            #pragma unroll
            for (int g = 0; g < 4; ++g)
                mx = fmaxf(mx, fmaxf(fmaxf(s[u][g].x, s[u][g].y), fmaxf(s[u][g].z, s[u][g].w)));
            mx = fmaxf(mx, __shfl_xor(mx, 16, 64));
            mx = fmaxf(mx, __shfl_xor(mx, 32, 64));
            float mnew = fmaxf(mrun[u], mx);
            alpha[u] = exp2f(mrun[u] - mnew);
            float p[16], rs = 0.f;
            #pragma unroll
            for (int g = 0; g < 4; ++g) {
                p[g*4+0] = exp2f(s[u][g].x - mnew);
                p[g*4+1] = exp2f(s[u][g].y - mnew);
                p[g*4+2] = exp2f(s[u][g].z - mnew);
                p[g*4+3] = exp2f(s[u][g].w - mnew);
                rs += (p[g*4+0] + p[g*4+1]) + (p[g*4+2] + p[g*4+3]);
            }
            rs += __shfl_xor(rs, 16, 64);
            rs += __shfl_xor(rs, 32, 64);
            lrun[u] = alpha[u] * lrun[u] + rs;
            mrun[u] = mnew;
            pf[u][0] = (f16x8){(f16)p[0],(f16)p[1],(f16)p[2],(f16)p[3],(f16)p[4],(f16)p[5],(f16)p[6],(f16)p[7]};
            pf[u][1] = (f16x8){(f16)p[8],(f16)p[9],(f16)p[10],(f16)p[11],(f16)p[12],(f16)p[13],(f16)p[14],(f16)p[15]};
        }
        #pragma unroll
        for (int u = 0; u < 2; ++u)
            #pragma unroll
            for (int cb = 0; cb < 8; ++cb) oacc[u][cb] *= alpha[u];
        #pragma unroll
        for (int k2 = 0; k2 < 2; ++k2)
            #pragma unroll
            for (int cb = 0; cb < 8; ++cb) {
                oacc[0][cb] = __builtin_amdgcn_mfma_f32_16x16x32_f16(vf[k2][cb], pf[0][k2], oacc[0][cb], 0, 0, 0);
                oacc[1][cb] = __builtin_amdgcn_mfma_f32_16x16x32_f16(vf[k2][cb], pf[1][k2], oacc[1][cb], 0, 0, 0);
            }
    }

    // ---- epilogue: normalize, final frame transform (M = L), store ----
    #pragma unroll
    for (int u = 0; u < 2; ++u) {
        int qrow = q0 + u * 16 + lq;
        float invl = 1.0f / lrun[u];
        const float* Lr = Lm + ((size_t)b * NSEQ + qrow) * 16;
        float* ob = out + ((size_t)bh * NSEQ + qrow) * CD;
        #pragma unroll
        for (int cb = 0; cb < 8; ++cb) {
            int c0 = cb * 16 + quad * 4;
            float o0 = oacc[u][cb].x*invl, o1 = oacc[u][cb].y*invl;
            float o2 = oacc[u][cb].z*invl, o3 = oacc[u][cb].w*invl;
            float4 r;
            if (c0 >= 8) {
                r.x = Lr[0] *o0 + Lr[1] *o1 + Lr[2] *o2 + Lr[3] *o3;
                r.y = Lr[4] *o0 + Lr[5] *o1 + Lr[6] *o2 + Lr[7] *o3;
                r.z = Lr[8] *o0 + Lr[9] *o1 + Lr[10]*o2 + Lr[11]*o3;
                r.w = Lr[12]*o0 + Lr[13]*o1 + Lr[14]*o2 + Lr[15]*o3;
            } else {
                r.x = o0; r.y = o1; r.z = o2; r.w = o3;
            }
            *(float4*)(ob + c0) = r;
        }
    }
}

extern "C" void kernel_launch(void* const* d_in, const int* in_sizes, int n_in,
                              void* d_out, int out_size, void* d_ws, size_t ws_size,
                              hipStream_t stream) {
    const float* q = (const float*)d_in[0];
    const float* k = (const float*)d_in[1];
    const float* v = (const float*)d_in[2];
    const float* L = (const float*)d_in[3];
    float* o = (float*)d_out;
    f16* khs = (f16*)d_ws;                       // 16.78 MB
    f16* vhs = khs + (size_t)64 * 131072;        // 16.78 MB
    dim3 grid1(64, 16);
    ipa_pre<<<grid1, 256, 0, stream>>>(k, v, L, khs, vhs);
    ipa_attn<<<1024, 128, 0, stream>>>(q, khs, vhs, L, o);
}